// Round 4
// baseline (50818.634 us; speedup 1.0000x reference)
//
#include <hip/hip_runtime.h>

namespace {

constexpr int Hn = 50;    // hidden size
constexpr int Bn = 2048;  // batch
constexpr int Tn = 512;   // sequence length

typedef float vf32 __attribute__((ext_vector_type(32)));
typedef float vf16 __attribute__((ext_vector_type(16)));
typedef float vf8  __attribute__((ext_vector_type(8)));
typedef float vf4  __attribute__((ext_vector_type(4)));

__device__ __forceinline__ float fsig(float x) {
  return 1.0f / (1.0f + __expf(-x));  // x<<0 -> exp=inf -> 0 : safe
}
__device__ __forceinline__ float ftanh(float x) {
  float a = fabsf(x);
  float e = __expf(-2.0f * a);        // in (0,1]
  float t = (1.0f - e) / (1.0f + e);
  return copysignf(t, x);
}

// ============================================================================
// 2-wave cooperative LSTM, weights in NAMED ext-vector SSA values (never an
// alloca -> guaranteed arch-VGPR residency; R1-R3 showed C arrays get demoted).
// Block = 128 threads = 2 waves, 4 batch elements.
//   wave 0 owns gates {i,f}, wave 1 owns {g,o}; lane q = cell q.
//   u = [x_t(50) ; h_{t-1}(50) ; pad(4)] stored k-major s_u[104][4]:
//   one broadcast ds_read_b128 yields u[k] for all 4 elems -> feeds 8 FMA.
// Weight regs/lane: 2 gates x 104 = 208 -> 1 wave/SIMD (512-reg budget).
// Gate exchange via s_g; wave p cell-updates elems {2p, 2p+1}. fp32 exact.
// ============================================================================

#define KBLK(WA, WB, NB, K0)                                   \
  _Pragma("unroll") for (int j = 0; j < NB; ++j) {             \
    const vf4 u = *(const vf4*)&s_u[(K0) + j][0];              \
    const float wAv = WA[j], wBv = WB[j];                      \
    const vf4 wa4 = {wAv, wAv, wAv, wAv};                      \
    const vf4 wb4 = {wBv, wBv, wBv, wBv};                      \
    aA = __builtin_elementwise_fma(wa4, u, aA);                \
    aB = __builtin_elementwise_fma(wb4, u, aB);                \
  }

// -------- Layers 2/3: input sequence [T][B][H], K = 104 --------
template <bool WRITE_H, bool DO_FC>
__global__ __launch_bounds__(128, 1) void lstm_mid(
    const float* __restrict__ xseq,  // [T][B][H] (may alias hseq: in-place ok)
    const float* __restrict__ wih,   // [4H][H]
    const float* __restrict__ whh,   // [4H][H]
    const float* __restrict__ bias,  // [4H]
    float* __restrict__ hseq,        // [T][B][H]
    const float* __restrict__ wfc,   // [H]
    const float* __restrict__ bfc,   // [1]
    float* __restrict__ out)         // [B]
{
  __shared__ float s_u[104][4];      // k-major: rows 0..49 x, 50..99 h, 100..103 pad
  __shared__ float s_g[4][4][52];    // [gate][elem][cell]

  const int lane = threadIdx.x & 63;
  const int p    = threadIdx.x >> 6;   // gate-pair: 0 -> {i,f}, 1 -> {g,o}
  const int eb   = blockIdx.x * 4;
  const bool act = lane < Hn;
  const int q    = act ? lane : 0;
  const int gA   = 2 * p, gB = 2 * p + 1;
  const int rA   = gA * Hn + q, rB = gB * Hn + q;
  const int le0  = 2 * p, le1 = 2 * p + 1;   // elems this wave cell-updates
  const int me0  = eb + le0, me1 = eb + le1;

  // concatenated row [Wih | Whh | 0pad], k in [0,104)
#define WCAT(ROW, K) \
  ((K) < 50 ? wih[(ROW)*Hn + (K)] : (K) < 100 ? whh[(ROW)*Hn + (K)-50] : 0.0f)
  vf32 wa0, wa1, wa2; vf8 wa3;
  vf32 wb0, wb1, wb2; vf8 wb3;
#pragma unroll
  for (int j = 0; j < 32; ++j) { wa0[j] = WCAT(rA, j);      wb0[j] = WCAT(rB, j); }
#pragma unroll
  for (int j = 0; j < 32; ++j) { wa1[j] = WCAT(rA, 32 + j); wb1[j] = WCAT(rB, 32 + j); }
#pragma unroll
  for (int j = 0; j < 32; ++j) { wa2[j] = WCAT(rA, 64 + j); wb2[j] = WCAT(rB, 64 + j); }
#pragma unroll
  for (int j = 0; j < 8; ++j)  { wa3[j] = WCAT(rA, 96 + j); wb3[j] = WCAT(rB, 96 + j); }
#undef WCAT
  const float bA = act ? bias[rA] : 0.f;
  const float bB = act ? bias[rB] : 0.f;

  for (int i = threadIdx.x; i < 104 * 4; i += 128) ((float*)s_u)[i] = 0.f;
  __syncthreads();
  for (int i = threadIdx.x; i < 4 * Hn; i += 128) {
    const int e = i / Hn, k = i % Hn;
    s_u[k][e] = xseq[((size_t)0 * Bn + eb + e) * Hn + k];
  }
  __syncthreads();

  float c0 = 0.f, c1 = 0.f, h0v = 0.f, h1v = 0.f;

#pragma unroll 1
  for (int t = 0; t < Tn; ++t) {
    // prefetch next x for my two elems (slot t+1; slot t written below)
    const int tn = (t + 1 < Tn) ? t + 1 : t;
    const float xn0 = act ? xseq[((size_t)tn * Bn + me0) * Hn + lane] : 0.f;
    const float xn1 = act ? xseq[((size_t)tn * Bn + me1) * Hn + lane] : 0.f;

    vf4 aA = {bA, bA, bA, bA};
    vf4 aB = {bB, bB, bB, bB};
    KBLK(wa0, wb0, 32, 0)
    KBLK(wa1, wb1, 32, 32)
    KBLK(wa2, wb2, 32, 64)
    KBLK(wa3, wb3, 8, 96)

    if (act) {
#pragma unroll
      for (int e = 0; e < 4; ++e) {
        s_g[gA][e][q] = aA[e];
        s_g[gB][e][q] = aB[e];
      }
    }
    __syncthreads();

    // wave p updates elems le0, le1
    {
      const float i0 = fsig(s_g[0][le0][q]), f0 = fsig(s_g[1][le0][q]);
      const float g0 = ftanh(s_g[2][le0][q]), o0 = fsig(s_g[3][le0][q]);
      c0  = fmaf(f0, c0, i0 * g0);
      h0v = o0 * ftanh(c0);
      const float i1 = fsig(s_g[0][le1][q]), f1 = fsig(s_g[1][le1][q]);
      const float g1 = ftanh(s_g[2][le1][q]), o1 = fsig(s_g[3][le1][q]);
      c1  = fmaf(f1, c1, i1 * g1);
      h1v = o1 * ftanh(c1);
    }
    if (act) {
      s_u[Hn + q][le0] = h0v;
      s_u[Hn + q][le1] = h1v;
      s_u[q][le0] = xn0;
      s_u[q][le1] = xn1;
      if (WRITE_H) {
        hseq[((size_t)t * Bn + me0) * Hn + lane] = h0v;
        hseq[((size_t)t * Bn + me1) * Hn + lane] = h1v;
      }
    }
    __syncthreads();
  }

  if (DO_FC) {
    const float wf = act ? wfc[q] : 0.f;
    float p0 = act ? h0v * wf : 0.f;
    float p1 = act ? h1v * wf : 0.f;
#pragma unroll
    for (int off = 32; off > 0; off >>= 1) {
      p0 += __shfl_xor(p0, off);
      p1 += __shfl_xor(p1, off);
    }
    if (lane == 0) {
      const float bv = bfc[0];
      out[me0] = p0 + bv;
      out[me1] = p1 + bv;
    }
  }
}

// -------- Layer 1: scalar input x[B][T], K = 52 --------
__global__ __launch_bounds__(128, 1) void lstm_first(
    const float* __restrict__ x,     // [B][T]
    const float* __restrict__ wih,   // [4H][1]
    const float* __restrict__ whh,   // [4H][H]
    const float* __restrict__ bias,  // [4H]
    float* __restrict__ hseq)        // [T][B][H]
{
  __shared__ float s_u[52][4];       // row 0 = x_t, rows 1..50 = h, 51 pad
  __shared__ float s_g[4][4][52];

  const int lane = threadIdx.x & 63;
  const int p    = threadIdx.x >> 6;
  const int eb   = blockIdx.x * 4;
  const bool act = lane < Hn;
  const int q    = act ? lane : 0;
  const int gA   = 2 * p, gB = 2 * p + 1;
  const int rA   = gA * Hn + q, rB = gB * Hn + q;
  const int le0  = 2 * p, le1 = 2 * p + 1;
  const int me0  = eb + le0, me1 = eb + le1;

  // row = [wih_scalar | Whh | 0pad], k in [0,52)
#define WCAT1(ROW, K) \
  ((K) == 0 ? wih[ROW] : (K) < 51 ? whh[(ROW)*Hn + (K)-1] : 0.0f)
  vf32 wa0; vf16 wa1; vf4 wa2;
  vf32 wb0; vf16 wb1; vf4 wb2;
#pragma unroll
  for (int j = 0; j < 32; ++j) { wa0[j] = WCAT1(rA, j);      wb0[j] = WCAT1(rB, j); }
#pragma unroll
  for (int j = 0; j < 16; ++j) { wa1[j] = WCAT1(rA, 32 + j); wb1[j] = WCAT1(rB, 32 + j); }
#pragma unroll
  for (int j = 0; j < 4; ++j)  { wa2[j] = WCAT1(rA, 48 + j); wb2[j] = WCAT1(rB, 48 + j); }
#undef WCAT1
  const float bA = act ? bias[rA] : 0.f;
  const float bB = act ? bias[rB] : 0.f;

  for (int i = threadIdx.x; i < 52 * 4; i += 128) ((float*)s_u)[i] = 0.f;
  __syncthreads();
  if (threadIdx.x < 4) s_u[0][threadIdx.x] = x[(size_t)(eb + threadIdx.x) * Tn + 0];
  __syncthreads();

  float c0 = 0.f, c1 = 0.f, h0v = 0.f, h1v = 0.f;

#pragma unroll 1
  for (int t = 0; t < Tn; ++t) {
    const int tn = (t + 1 < Tn) ? t + 1 : t;
    // wave-uniform scalar loads (SMEM-eligible): next x for my two elems
    const float xn0 = x[(size_t)me0 * Tn + tn];
    const float xn1 = x[(size_t)me1 * Tn + tn];

    vf4 aA = {bA, bA, bA, bA};
    vf4 aB = {bB, bB, bB, bB};
    KBLK(wa0, wb0, 32, 0)
    KBLK(wa1, wb1, 16, 32)
    KBLK(wa2, wb2, 4, 48)

    if (act) {
#pragma unroll
      for (int e = 0; e < 4; ++e) {
        s_g[gA][e][q] = aA[e];
        s_g[gB][e][q] = aB[e];
      }
    }
    __syncthreads();

    {
      const float i0 = fsig(s_g[0][le0][q]), f0 = fsig(s_g[1][le0][q]);
      const float g0 = ftanh(s_g[2][le0][q]), o0 = fsig(s_g[3][le0][q]);
      c0  = fmaf(f0, c0, i0 * g0);
      h0v = o0 * ftanh(c0);
      const float i1 = fsig(s_g[0][le1][q]), f1 = fsig(s_g[1][le1][q]);
      const float g1 = ftanh(s_g[2][le1][q]), o1 = fsig(s_g[3][le1][q]);
      c1  = fmaf(f1, c1, i1 * g1);
      h1v = o1 * ftanh(c1);
    }
    if (act) {
      s_u[1 + q][le0] = h0v;
      s_u[1 + q][le1] = h1v;
      hseq[((size_t)t * Bn + me0) * Hn + lane] = h0v;
      hseq[((size_t)t * Bn + me1) * Hn + lane] = h1v;
    }
    if (lane == 0) {
      s_u[0][le0] = xn0;
      s_u[0][le1] = xn1;
    }
    __syncthreads();
  }
}

}  // namespace

extern "C" void kernel_launch(void* const* d_in, const int* in_sizes, int n_in,
                              void* d_out, int out_size, void* d_ws, size_t ws_size,
                              hipStream_t stream) {
  const float* x    = (const float*)d_in[0];
  const float* wih1 = (const float*)d_in[1];
  const float* whh1 = (const float*)d_in[2];
  const float* b1   = (const float*)d_in[3];
  const float* wih2 = (const float*)d_in[4];
  const float* whh2 = (const float*)d_in[5];
  const float* b2   = (const float*)d_in[6];
  const float* wih3 = (const float*)d_in[7];
  const float* whh3 = (const float*)d_in[8];
  const float* b3   = (const float*)d_in[9];
  const float* wfc  = (const float*)d_in[10];
  const float* bfc  = (const float*)d_in[11];
  float* out = (float*)d_out;

  float* buf = (float*)d_ws;  // [T][B][H] fp32 = 200 MiB (fits; verified R1/R2)

  dim3 grid(Bn / 4), blk(128);  // 512 blocks x 2 waves; 4 elems/block
  lstm_first<<<grid, blk, 0, stream>>>(x, wih1, whh1, b1, buf);
  lstm_mid<true, false><<<grid, blk, 0, stream>>>(
      buf, wih2, whh2, b2, buf, nullptr, nullptr, nullptr);
  lstm_mid<false, true><<<grid, blk, 0, stream>>>(
      buf, wih3, whh3, b3, nullptr, wfc, bfc, out);
}

// Round 5
// 2907.873 us; speedup vs baseline: 17.4762x; 17.4762x over previous
//
#include <hip/hip_runtime.h>

namespace {

constexpr int Hn = 50;    // hidden size
constexpr int Bn = 2048;  // batch
constexpr int Tn = 512;   // sequence length

typedef short short8 __attribute__((ext_vector_type(8)));
typedef float f32x4 __attribute__((ext_vector_type(4)));

__device__ __forceinline__ unsigned bcu(float f) { return __builtin_bit_cast(unsigned, f); }
__device__ __forceinline__ float bcf(unsigned u) { return __builtin_bit_cast(float, u); }

__device__ __forceinline__ float fsig(float x) {
  return 1.0f / (1.0f + __expf(-x));  // x<<0 -> exp=inf -> 0 : safe
}
__device__ __forceinline__ float ftanh(float x) {
  float a = fabsf(x);
  float e = __expf(-2.0f * a);        // in (0,1]
  float t = (1.0f - e) / (1.0f + e);
  return copysignf(t, x);
}

#define MF(a, b, c) __builtin_amdgcn_mfma_f32_16x16x32_bf16(a, b, c, 0, 0, 0)

// ============================================================================
// MFMA LSTM. Block = 256 thr = 4 waves = 16 batch elements. 128 blocks.
// Per step: gates[16 x 208] = u[16 x 128] @ W^T[128 x 208] via 16x16x32 bf16
// MFMA; 13 N-tiles split over 4 waves (w, w+4, w+8, w+12). Weights are
// persistent B-fragments in registers (MFMA reads VGPR or AGPR directly ->
// immune to the R1-R4 demotion/spill pathology). fp32 accuracy recovered by
// split-bf16: w=wh+wl, u=uh+ul, gates = Ah*Bh + Al*Bh + Ah*Bl (err ~2^-16).
// Gate tiles -> LDS s_g (C/D layout: col=lane&15, row=quad*4+reg) -> fp32
// cell update (c thread-resident) -> h split back into LDS A-planes
// (A layout: m=lane&15, k=quad*8+j). x(t+1) prefetched during MFMA stage.
// K layout: FIRST: k0=x, k1..50=h, rest 0 (NC=2). MID: k0..49=x, 50..99=h,
// rest 0 (NC=4). Zero weight rows make pad-K/pad-N contributions exact 0.
// ============================================================================

#define LOADC(I, C)                                                       \
  if (NC > (C) && tl##I < 13) {                                           \
    const int nn = tl##I * 16 + nl;                                       \
    _Pragma("unroll") for (int j = 0; j < 8; ++j) {                       \
      const int k = (C) * 32 + quad * 8 + j;                              \
      float wv = 0.f;                                                     \
      if (nn < 200) {                                                     \
        if (FIRST) {                                                      \
          if (k == 0) wv = wih[nn];                                       \
          else if (k <= Hn) wv = whh[nn * Hn + k - 1];                    \
        } else {                                                          \
          if (k < Hn) wv = wih[nn * Hn + k];                              \
          else if (k < 2 * Hn) wv = whh[nn * Hn + k - Hn];                \
        }                                                                 \
      }                                                                   \
      const unsigned u = bcu(wv);                                         \
      bh##I##C[j] = (short)(u >> 16);                                     \
      bl##I##C[j] = (short)(bcu(wv - bcf(u & 0xFFFF0000u)) >> 16);        \
    }                                                                     \
  }

#define TILEMM(I, C, AH, AL)                                              \
  if (tl##I < 13) {                                                       \
    acc##I = MF(AH, bh##I##C, acc##I);                                    \
    acc##I = MF(AL, bh##I##C, acc##I);                                    \
    acc##I = MF(AH, bl##I##C, acc##I);                                    \
  }

#define CHUNK(C)                                                          \
  if (NC > (C)) {                                                         \
    const short8 ah = *(const short8*)&s_ah[nl][(C) * 32 + quad * 8];     \
    const short8 al = *(const short8*)&s_al[nl][(C) * 32 + quad * 8];     \
    TILEMM(0, C, ah, al)                                                  \
    TILEMM(1, C, ah, al)                                                  \
    TILEMM(2, C, ah, al)                                                  \
    TILEMM(3, C, ah, al)                                                  \
  }

#define WRITE_X()                                                         \
  if (FIRST) {                                                            \
    if (tid < 16) {                                                       \
      const unsigned u = bcu(xp[0]);                                      \
      s_ah[tid][0] = (short)(u >> 16);                                    \
      s_al[tid][0] = (short)(bcu(xp[0] - bcf(u & 0xFFFF0000u)) >> 16);    \
    }                                                                     \
  } else {                                                                \
    _Pragma("unroll") for (int r = 0; r < 4; ++r) {                       \
      const int k = gu + 16 * r;                                          \
      if (k < Hn) {                                                       \
        const unsigned u = bcu(xp[r]);                                    \
        s_ah[mu][k] = (short)(u >> 16);                                   \
        s_al[mu][k] = (short)(bcu(xp[r] - bcf(u & 0xFFFF0000u)) >> 16);   \
      }                                                                   \
    }                                                                     \
  }

template <bool FIRST, bool WRITE_H, bool DO_FC>
__global__ __launch_bounds__(256, 1) void lstm_mfma(
    const float* xin,                 // FIRST: x[B][T]; else prev hseq [T][B][H]
    const float* __restrict__ wih,    // FIRST: [4H][1]; else [4H][H]
    const float* __restrict__ whh,    // [4H][H]
    const float* __restrict__ bias,   // [4H]
    float* hout,                      // [T][B][H] (may alias xin: in-place)
    const float* __restrict__ wfc,    // [H]
    const float* __restrict__ bfc,    // [1]
    float* __restrict__ out)          // [B]
{
  constexpr int NC = FIRST ? 2 : 4;   // K chunks of 32 (K=64 / K=128 padded)
  constexpr int KH0 = FIRST ? 1 : 50; // k offset of the h region

  __shared__ __align__(16) short s_ah[16][136];  // A-plane hi (8-short row pad)
  __shared__ __align__(16) short s_al[16][136];  // A-plane lo
  __shared__ __align__(16) float s_g[208][20];   // gates [n][m] (+4 pad)

  const int tid  = threadIdx.x;
  const int w    = tid >> 6;          // wave id
  const int quad = (tid >> 4) & 3;    // lane>>4 within wave
  const int nl   = tid & 15;          // lane&15: n for B/D, m for A
  const int eb   = blockIdx.x * 16;   // batch base
  const int mu   = tid & 15;          // cell-update: element row
  const int gu   = tid >> 4;          // cell-update: k/q group (0..15)

  const int tl0 = w, tl1 = w + 4, tl2 = w + 8, tl3 = w + 12;

  // ---- persistent B-fragments (named SSA values; MFMA-direct operands) ----
  short8 bh00 = {0}, bh01 = {0}, bh02 = {0}, bh03 = {0};
  short8 bh10 = {0}, bh11 = {0}, bh12 = {0}, bh13 = {0};
  short8 bh20 = {0}, bh21 = {0}, bh22 = {0}, bh23 = {0};
  short8 bh30 = {0}, bh31 = {0}, bh32 = {0}, bh33 = {0};
  short8 bl00 = {0}, bl01 = {0}, bl02 = {0}, bl03 = {0};
  short8 bl10 = {0}, bl11 = {0}, bl12 = {0}, bl13 = {0};
  short8 bl20 = {0}, bl21 = {0}, bl22 = {0}, bl23 = {0};
  short8 bl30 = {0}, bl31 = {0}, bl32 = {0}, bl33 = {0};
  LOADC(0, 0) LOADC(0, 1) LOADC(0, 2) LOADC(0, 3)
  LOADC(1, 0) LOADC(1, 1) LOADC(1, 2) LOADC(1, 3)
  LOADC(2, 0) LOADC(2, 1) LOADC(2, 2) LOADC(2, 3)
  LOADC(3, 0) LOADC(3, 1) LOADC(3, 2) LOADC(3, 3)

  // ---- per-thread cell-update constants/state ----
  float bi[4], bfr[4], bg[4], bo[4], cst[4] = {0, 0, 0, 0}, hl[4] = {0, 0, 0, 0};
#pragma unroll
  for (int r = 0; r < 4; ++r) {
    const int q = gu + 16 * r;
    bi[r] = bfr[r] = bg[r] = bo[r] = 0.f;
    if (q < Hn) {
      bi[r]  = bias[q];
      bfr[r] = bias[Hn + q];
      bg[r]  = bias[2 * Hn + q];
      bo[r]  = bias[3 * Hn + q];
    }
  }

  // ---- zero A-planes (h_0 = 0, pad-K = 0), then stage x(0) ----
  for (int i = tid; i < 16 * 136; i += 256) {
    (&s_ah[0][0])[i] = 0;
    (&s_al[0][0])[i] = 0;
  }
  __syncthreads();
  float xp[4] = {0, 0, 0, 0};
  if (FIRST) {
    if (tid < 16) xp[0] = xin[(size_t)(eb + tid) * Tn + 0];
  } else {
#pragma unroll
    for (int r = 0; r < 4; ++r) {
      const int k = gu + 16 * r;
      if (k < Hn) xp[r] = xin[((size_t)0 * Bn + eb + mu) * Hn + k];
    }
  }
  WRITE_X();

#pragma unroll 1
  for (int t = 0; t < Tn; ++t) {
    __syncthreads();  // (A) A-planes ready for step t

    // prefetch x(t+1) (overlaps MFMA + cell stages)
    const int tn = (t + 1 < Tn) ? t + 1 : t;
    if (FIRST) {
      if (tid < 16) xp[0] = xin[(size_t)(eb + tid) * Tn + tn];
    } else {
#pragma unroll
      for (int r = 0; r < 4; ++r) {
        const int k = gu + 16 * r;
        if (k < Hn) xp[r] = xin[((size_t)tn * Bn + eb + mu) * Hn + k];
      }
    }

    // ---- MFMA stage: gates for this block's 16 elements ----
    f32x4 acc0 = {0, 0, 0, 0}, acc1 = {0, 0, 0, 0};
    f32x4 acc2 = {0, 0, 0, 0}, acc3 = {0, 0, 0, 0};
    CHUNK(0) CHUNK(1) CHUNK(2) CHUNK(3)
    if (tl0 < 13) *(f32x4*)&s_g[tl0 * 16 + nl][quad * 4] = acc0;
    if (tl1 < 13) *(f32x4*)&s_g[tl1 * 16 + nl][quad * 4] = acc1;
    if (tl2 < 13) *(f32x4*)&s_g[tl2 * 16 + nl][quad * 4] = acc2;
    if (tl3 < 13) *(f32x4*)&s_g[tl3 * 16 + nl][quad * 4] = acc3;

    __syncthreads();  // (B) gates ready

    // ---- fp32 cell update: thread (mu, gu) owns cells q = gu + 16r ----
#pragma unroll
    for (int r = 0; r < 4; ++r) {
      const int q = gu + 16 * r;
      if (q < Hn) {
        const float zi = s_g[q][mu] + bi[r];
        const float zf = s_g[Hn + q][mu] + bfr[r];
        const float zg = s_g[2 * Hn + q][mu] + bg[r];
        const float zo = s_g[3 * Hn + q][mu] + bo[r];
        const float I = fsig(zi), F = fsig(zf), G = ftanh(zg), O = fsig(zo);
        cst[r] = fmaf(F, cst[r], I * G);
        const float hv = O * ftanh(cst[r]);
        hl[r] = hv;
        const unsigned u = bcu(hv);
        s_ah[mu][KH0 + q] = (short)(u >> 16);
        s_al[mu][KH0 + q] = (short)(bcu(hv - bcf(u & 0xFFFF0000u)) >> 16);
        if (WRITE_H) hout[((size_t)t * Bn + eb + mu) * Hn + q] = hv;
      }
    }
    WRITE_X();  // stage x(t+1); safe: all A-plane reads for t done before (B)
  }

  if (DO_FC) {
    __syncthreads();  // protect s_g reuse from last cell-stage reads
    float p = 0.f;
#pragma unroll
    for (int r = 0; r < 4; ++r) {
      const int q = gu + 16 * r;
      if (q < Hn) p += hl[r] * wfc[q];
    }
    s_g[gu][mu] = p;
    __syncthreads();
    if (tid < 16) {
      float s = bfc[0];
#pragma unroll
      for (int j = 0; j < 16; ++j) s += s_g[j][tid];
      out[eb + tid] = s;
    }
  }
}

}  // namespace

extern "C" void kernel_launch(void* const* d_in, const int* in_sizes, int n_in,
                              void* d_out, int out_size, void* d_ws, size_t ws_size,
                              hipStream_t stream) {
  const float* x    = (const float*)d_in[0];
  const float* wih1 = (const float*)d_in[1];
  const float* whh1 = (const float*)d_in[2];
  const float* b1   = (const float*)d_in[3];
  const float* wih2 = (const float*)d_in[4];
  const float* whh2 = (const float*)d_in[5];
  const float* b2   = (const float*)d_in[6];
  const float* wih3 = (const float*)d_in[7];
  const float* whh3 = (const float*)d_in[8];
  const float* b3   = (const float*)d_in[9];
  const float* wfc  = (const float*)d_in[10];
  const float* bfc  = (const float*)d_in[11];
  float* out = (float*)d_out;

  float* buf = (float*)d_ws;  // hseq fp32 [T][B][H] = 200 MiB (fits; R1-R3)

  dim3 grid(Bn / 16), blk(256);  // 128 blocks x 4 waves, 16 elems/block
  lstm_mfma<true, true, false><<<grid, blk, 0, stream>>>(
      x, wih1, whh1, b1, buf, nullptr, nullptr, nullptr);
  lstm_mfma<false, true, false><<<grid, blk, 0, stream>>>(
      buf, wih2, whh2, b2, buf, nullptr, nullptr, nullptr);
  lstm_mfma<false, false, true><<<grid, blk, 0, stream>>>(
      buf, wih3, whh3, b3, nullptr, wfc, bfc, out);
}